// Round 5
// baseline (1302.105 us; speedup 1.0000x reference)
//
#include <hip/hip_runtime.h>

#define SCAN_B 1024
#define NGRAPH 128
typedef unsigned short u16;
typedef unsigned int u32;
typedef u32 u32x4 __attribute__((ext_vector_type(4)));

__device__ __forceinline__ float bf2f(u16 u) {
  return __uint_as_float(((u32)u) << 16);
}
__device__ __forceinline__ u16 f2bf(float f) {
  u32 u = __float_as_uint(f);
  return (u16)((u + 0x7fffu + ((u >> 16) & 1u)) >> 16);
}
__device__ __forceinline__ float bflo(u32 w) { return __uint_as_float(w << 16); }
__device__ __forceinline__ float bfhi(u32 w) { return __uint_as_float(w & 0xffff0000u); }

// ---------------- node encoder: h = x @ W(32x64) + b  -> bf16 --------------
__global__ __launch_bounds__(256) void node_enc_kernel(
    const float* __restrict__ x, const float* __restrict__ W,
    const float* __restrict__ b, u16* __restrict__ zb, int N)
{
  int lane = threadIdx.x & 63;
  int wave = (blockIdx.x * blockDim.x + threadIdx.x) >> 6;
  int nw = (gridDim.x * blockDim.x) >> 6;
  float wcol[32];
#pragma unroll
  for (int k = 0; k < 32; ++k) wcol[k] = W[k * 64 + lane];
  float bb = b[lane];
  for (int n = wave; n < N; n += nw) {
    const float4* xr = (const float4*)(x + (size_t)n * 32);
    float acc = bb;
#pragma unroll
    for (int c = 0; c < 8; ++c) {
      float4 v = xr[c];
      acc = fmaf(v.x, wcol[4 * c + 0], acc);
      acc = fmaf(v.y, wcol[4 * c + 1], acc);
      acc = fmaf(v.z, wcol[4 * c + 2], acc);
      acc = fmaf(v.w, wcol[4 * c + 3], acc);
    }
    zb[(size_t)n * 64 + lane] = f2bf(acc);
  }
}

// ---------------- CSR build ------------------------------------------------
__global__ __launch_bounds__(256) void count_kernel(
    const int* __restrict__ dst, int* __restrict__ deg, int E)
{
  int e = blockIdx.x * blockDim.x + threadIdx.x;
  if (e < E) atomicAdd(&deg[dst[e]], 1);
}

__global__ __launch_bounds__(SCAN_B) void scan1_kernel(
    const int* __restrict__ deg, int* __restrict__ rowp,
    int* __restrict__ bsum, int N)
{
  __shared__ int s[SCAN_B];
  int tid = threadIdx.x;
  int i = blockIdx.x * SCAN_B + tid;
  int v = (i < N) ? deg[i] : 0;
  s[tid] = v;
  __syncthreads();
  for (int off = 1; off < SCAN_B; off <<= 1) {
    int t = (tid >= off) ? s[tid - off] : 0;
    __syncthreads();
    s[tid] += t;
    __syncthreads();
  }
  if (i < N) rowp[i] = s[tid] - v;          // exclusive
  if (tid == SCAN_B - 1) bsum[blockIdx.x] = s[tid];
}

__global__ __launch_bounds__(128) void scan2_kernel(int* __restrict__ bsum, int NB)
{
  __shared__ int s[128];
  int tid = threadIdx.x;
  int v = (tid < NB) ? bsum[tid] : 0;
  s[tid] = v;
  __syncthreads();
  for (int off = 1; off < 128; off <<= 1) {
    int t = (tid >= off) ? s[tid - off] : 0;
    __syncthreads();
    s[tid] += t;
    __syncthreads();
  }
  if (tid < NB) bsum[tid] = s[tid] - v;     // exclusive block offsets
}

__global__ __launch_bounds__(SCAN_B) void scan3_kernel(
    int* __restrict__ rowp, const int* __restrict__ bsum, int N, int E)
{
  int i = blockIdx.x * SCAN_B + threadIdx.x;
  if (i < N) rowp[i] += bsum[blockIdx.x];
  if (i == 0) rowp[N] = E;
}

// scatter + attr bf16 convert into CSR order
__global__ __launch_bounds__(256) void scatter_conv_kernel(
    const int* __restrict__ dst, const int* __restrict__ src,
    const float4* __restrict__ attr4, const int* __restrict__ rowp,
    int* __restrict__ fill, int* __restrict__ src_s,
    u32x4* __restrict__ attr_s4, int* __restrict__ eids, int E)
{
  int e = blockIdx.x * blockDim.x + threadIdx.x;
  if (e >= E) return;
  int d = dst[e];
  int p = rowp[d] + atomicAdd(&fill[d], 1);
  src_s[p] = src[e];
  if (eids) eids[p] = e;
  if (attr_s4) {
    float4 a0 = attr4[(size_t)e * 4 + 0];
    float4 a1 = attr4[(size_t)e * 4 + 1];
    float4 a2 = attr4[(size_t)e * 4 + 2];
    float4 a3 = attr4[(size_t)e * 4 + 3];
    u32x4 lo, hi;
    lo[0] = (u32)f2bf(a0.x) | ((u32)f2bf(a0.y) << 16);
    lo[1] = (u32)f2bf(a0.z) | ((u32)f2bf(a0.w) << 16);
    lo[2] = (u32)f2bf(a1.x) | ((u32)f2bf(a1.y) << 16);
    lo[3] = (u32)f2bf(a1.z) | ((u32)f2bf(a1.w) << 16);
    hi[0] = (u32)f2bf(a2.x) | ((u32)f2bf(a2.y) << 16);
    hi[1] = (u32)f2bf(a2.z) | ((u32)f2bf(a2.w) << 16);
    hi[2] = (u32)f2bf(a3.x) | ((u32)f2bf(a3.y) << 16);
    hi[3] = (u32)f2bf(a3.z) | ((u32)f2bf(a3.w) << 16);
    attr_s4[(size_t)p * 2 + 0] = lo;
    attr_s4[(size_t)p * 2 + 1] = hi;
  }
}

// ---------------- gather (pair-packed, recompute edge enc from attr_s) -----
// g[i] = hval(z[i]) + sum_{e: dst=i} relu(hval(z[src_e]) + attr_e @ eW + eb)
__global__ __launch_bounds__(256, 4) void gather_kernel(
    const u32* __restrict__ z32, const float* __restrict__ scsh,
    const u32x4* __restrict__ attr_s4, const int* __restrict__ srcv,
    const int* __restrict__ rowp, const float* __restrict__ eW,
    const float* __restrict__ eb_, float* __restrict__ g, int N, int use_bn)
{
  int lane = threadIdx.x & 63;
  int node = (blockIdx.x * blockDim.x + threadIdx.x) >> 6;
  if (node >= N) return;
  int c = lane & 31, hi = lane >> 5;

  // weight columns for channels 2c, 2c+1
  float wx[16], wy[16];
#pragma unroll
  for (int k = 0; k < 16; ++k) {
    float2 w2 = *(const float2*)&eW[k * 64 + 2 * c];
    wx[k] = w2.x; wy[k] = w2.y;
  }
  float2 eb2 = *(const float2*)&eb_[2 * c];
  float2 sc2 = make_float2(1.f, 1.f), sh2 = make_float2(0.f, 0.f);
  if (use_bn) {
    sc2 = *(const float2*)&scsh[2 * c];
    sh2 = *(const float2*)&scsh[64 + 2 * c];
  }

  // edot for this lane's 2 channels from packed attr (8 u32 = 16 bf16)
  auto edot2 = [&](u32x4 lo, u32x4 hb, float& m0, float& m1) {
    m0 = eb2.x; m1 = eb2.y;
    float a;
    a = bflo(lo[0]); m0 = fmaf(a, wx[0], m0);  m1 = fmaf(a, wy[0], m1);
    a = bfhi(lo[0]); m0 = fmaf(a, wx[1], m0);  m1 = fmaf(a, wy[1], m1);
    a = bflo(lo[1]); m0 = fmaf(a, wx[2], m0);  m1 = fmaf(a, wy[2], m1);
    a = bfhi(lo[1]); m0 = fmaf(a, wx[3], m0);  m1 = fmaf(a, wy[3], m1);
    a = bflo(lo[2]); m0 = fmaf(a, wx[4], m0);  m1 = fmaf(a, wy[4], m1);
    a = bfhi(lo[2]); m0 = fmaf(a, wx[5], m0);  m1 = fmaf(a, wy[5], m1);
    a = bflo(lo[3]); m0 = fmaf(a, wx[6], m0);  m1 = fmaf(a, wy[6], m1);
    a = bfhi(lo[3]); m0 = fmaf(a, wx[7], m0);  m1 = fmaf(a, wy[7], m1);
    a = bflo(hb[0]); m0 = fmaf(a, wx[8], m0);  m1 = fmaf(a, wy[8], m1);
    a = bfhi(hb[0]); m0 = fmaf(a, wx[9], m0);  m1 = fmaf(a, wy[9], m1);
    a = bflo(hb[1]); m0 = fmaf(a, wx[10], m0); m1 = fmaf(a, wy[10], m1);
    a = bfhi(hb[1]); m0 = fmaf(a, wx[11], m0); m1 = fmaf(a, wy[11], m1);
    a = bflo(hb[2]); m0 = fmaf(a, wx[12], m0); m1 = fmaf(a, wy[12], m1);
    a = bfhi(hb[2]); m0 = fmaf(a, wx[13], m0); m1 = fmaf(a, wy[13], m1);
    a = bflo(hb[3]); m0 = fmaf(a, wx[14], m0); m1 = fmaf(a, wy[14], m1);
    a = bfhi(hb[3]); m0 = fmaf(a, wx[15], m0); m1 = fmaf(a, wy[15], m1);
  };

  float accx, accy;
  {
    u32 zu = z32[(size_t)node * 32 + c];
    float z0 = bflo(zu), z1 = bfhi(zu);
    float h0, h1;
    if (use_bn) {
      h0 = fmaxf(fmaf(z0, sc2.x, sh2.x), 0.f);
      h1 = fmaxf(fmaf(z1, sc2.y, sh2.y), 0.f);
    } else { h0 = z0; h1 = z1; }
    accx = hi ? 0.f : h0;
    accy = hi ? 0.f : h1;
  }

  const int j0 = rowp[node], j1 = rowp[node + 1];
  for (int base = j0; base < j1; base += 64) {
    int nb = j1 - base; if (nb > 64) nb = 64;
    int iv = (lane < nb) ? srcv[base + lane] : 0;
    int np = nb >> 1;
    int t = 0;
    for (; t + 4 <= np; t += 4) {
      int ss[4]; u32 zu[4]; u32x4 alo[4], ahi[4];
#pragma unroll
      for (int q = 0; q < 4; ++q) ss[q] = __shfl(iv, 2 * (t + q) + hi, 64);
#pragma unroll
      for (int q = 0; q < 4; ++q) zu[q] = z32[(size_t)ss[q] * 32 + c];
#pragma unroll
      for (int q = 0; q < 4; ++q) {
        size_t j = (size_t)(base + 2 * (t + q) + hi) * 2;
        alo[q] = __builtin_nontemporal_load(&attr_s4[j]);
        ahi[q] = __builtin_nontemporal_load(&attr_s4[j + 1]);
      }
#pragma unroll
      for (int q = 0; q < 4; ++q) {
        float m0, m1;
        edot2(alo[q], ahi[q], m0, m1);
        float z0 = bflo(zu[q]), z1 = bfhi(zu[q]);
        float h0, h1;
        if (use_bn) {
          h0 = fmaxf(fmaf(z0, sc2.x, sh2.x), 0.f);
          h1 = fmaxf(fmaf(z1, sc2.y, sh2.y), 0.f);
        } else { h0 = z0; h1 = z1; }
        accx += fmaxf(h0 + m0, 0.f);
        accy += fmaxf(h1 + m1, 0.f);
      }
    }
    for (; t < np; ++t) {
      int s = __shfl(iv, 2 * t + hi, 64);
      u32 zu = z32[(size_t)s * 32 + c];
      size_t j = (size_t)(base + 2 * t + hi) * 2;
      u32x4 alo = __builtin_nontemporal_load(&attr_s4[j]);
      u32x4 ahi = __builtin_nontemporal_load(&attr_s4[j + 1]);
      float m0, m1;
      edot2(alo, ahi, m0, m1);
      float z0 = bflo(zu), z1 = bfhi(zu);
      float h0, h1;
      if (use_bn) {
        h0 = fmaxf(fmaf(z0, sc2.x, sh2.x), 0.f);
        h1 = fmaxf(fmaf(z1, sc2.y, sh2.y), 0.f);
      } else { h0 = z0; h1 = z1; }
      accx += fmaxf(h0 + m0, 0.f);
      accy += fmaxf(h1 + m1, 0.f);
    }
    if (nb & 1) {
      int s = __shfl(iv, nb - 1, 64);
      u32 zu = z32[(size_t)s * 32 + c];
      size_t j = (size_t)(base + nb - 1) * 2;
      u32x4 alo = __builtin_nontemporal_load(&attr_s4[j]);
      u32x4 ahi = __builtin_nontemporal_load(&attr_s4[j + 1]);
      float m0, m1;
      edot2(alo, ahi, m0, m1);
      float z0 = bflo(zu), z1 = bfhi(zu);
      float h0, h1;
      if (use_bn) {
        h0 = fmaxf(fmaf(z0, sc2.x, sh2.x), 0.f);
        h1 = fmaxf(fmaf(z1, sc2.y, sh2.y), 0.f);
      } else { h0 = z0; h1 = z1; }
      float a0 = fmaxf(h0 + m0, 0.f);
      float a1 = fmaxf(h1 + m1, 0.f);
      accx += hi ? 0.f : a0;
      accy += hi ? 0.f : a1;
    }
  }
  accx += __shfl_xor(accx, 32, 64);
  accy += __shfl_xor(accy, 32, 64);
  if (!hi) {
    float2 r; r.x = accx; r.y = accy;
    *(float2*)(g + (size_t)node * 64 + 2 * c) = r;
  }
}

// ---------------- fallback gather (non-sorted, f32 attr recompute) ---------
__global__ __launch_bounds__(256) void gather_fallback_kernel(
    const u16* __restrict__ zb, const float* __restrict__ scsh,
    const int* __restrict__ srcv, const int* __restrict__ eids,
    const int* __restrict__ rowp, const float* __restrict__ attr,
    const float* __restrict__ eW, const float* __restrict__ eb_,
    float* __restrict__ g, int N, int use_bn)
{
  int lane = threadIdx.x & 63;
  int node = (blockIdx.x * blockDim.x + threadIdx.x) >> 6;
  if (node >= N) return;
  float sc = 1.f, sh = 0.f;
  if (use_bn) { sc = scsh[lane]; sh = scsh[64 + lane]; }
  auto hval = [&](float zz) -> float {
    float v = fmaf(zz, sc, sh);
    return use_bn ? fmaxf(v, 0.f) : v;
  };
  float wcol[16];
#pragma unroll
  for (int k = 0; k < 16; ++k) wcol[k] = eW[k * 64 + lane];
  float eb = eb_[lane];
  const int j0 = rowp[node], j1 = rowp[node + 1];
  float acc = hval(bf2f(zb[(size_t)node * 64 + lane]));
  for (int j = j0; j < j1; ++j) {
    int eid = eids[j];
    int s = srcv[j];
    const float4* ar = (const float4*)(attr + (size_t)eid * 16);
    float4 a0 = ar[0], a1 = ar[1], a2 = ar[2], a3 = ar[3];
    float m = eb;
    m = fmaf(a0.x, wcol[0], m);  m = fmaf(a0.y, wcol[1], m);
    m = fmaf(a0.z, wcol[2], m);  m = fmaf(a0.w, wcol[3], m);
    m = fmaf(a1.x, wcol[4], m);  m = fmaf(a1.y, wcol[5], m);
    m = fmaf(a1.z, wcol[6], m);  m = fmaf(a1.w, wcol[7], m);
    m = fmaf(a2.x, wcol[8], m);  m = fmaf(a2.y, wcol[9], m);
    m = fmaf(a2.z, wcol[10], m); m = fmaf(a2.w, wcol[11], m);
    m = fmaf(a3.x, wcol[12], m); m = fmaf(a3.y, wcol[13], m);
    m = fmaf(a3.z, wcol[14], m); m = fmaf(a3.w, wcol[15], m);
    acc += fmaxf(hval(bf2f(zb[(size_t)s * 64 + lane])) + m, 0.f);
  }
  g[(size_t)node * 64 + lane] = acc;
}

// ---------------- fused MLP (two 64x64 matmuls) + BN stats -----------------
__global__ __launch_bounds__(256, 2) void mlp_fused_kernel(
    const float* __restrict__ g, u16* __restrict__ zb,
    const float* __restrict__ W1, const float* __restrict__ b1,
    const float* __restrict__ W2, const float* __restrict__ b2,
    float* __restrict__ stat, int N)
{
  __shared__ float sred[2][4][64];
  int tid = threadIdx.x, lane = tid & 63, w = tid >> 6;
  int row = blockIdx.x * 256 + tid;
  bool active = row < N;
  int r = active ? row : (N - 1);

  float y1[64];
#pragma unroll
  for (int d = 0; d < 64; ++d) y1[d] = b1[d];
  const float4* gr = (const float4*)(g + (size_t)r * 64);
  for (int kk = 0; kk < 16; ++kk) {
    float4 v = gr[kk];
    const float* wp = W1 + kk * 256;
#pragma unroll
    for (int d = 0; d < 64; ++d)
      y1[d] += fmaf(v.x, wp[d], fmaf(v.y, wp[64 + d],
               fmaf(v.z, wp[128 + d], v.w * wp[192 + d])));
  }
#pragma unroll
  for (int d = 0; d < 64; ++d) y1[d] = fmaxf(y1[d], 0.f);

  float y2[64];
#pragma unroll
  for (int d = 0; d < 64; ++d) y2[d] = b2[d];
  for (int kk = 0; kk < 16; ++kk) {
    const float* wp = W2 + kk * 256;
    float vx = y1[4 * kk], vy = y1[4 * kk + 1];
    float vz = y1[4 * kk + 2], vw = y1[4 * kk + 3];
#pragma unroll
    for (int d = 0; d < 64; ++d)
      y2[d] += fmaf(vx, wp[d], fmaf(vy, wp[64 + d],
               fmaf(vz, wp[128 + d], vw * wp[192 + d])));
  }

  if (active) {
    u32 packed[32];
#pragma unroll
    for (int c = 0; c < 32; ++c)
      packed[c] = (u32)f2bf(y2[2 * c]) | ((u32)f2bf(y2[2 * c + 1]) << 16);
    uint4* zr = (uint4*)(zb + (size_t)row * 64);
#pragma unroll
    for (int c = 0; c < 8; ++c)
      zr[c] = make_uint4(packed[4 * c], packed[4 * c + 1],
                         packed[4 * c + 2], packed[4 * c + 3]);
  }

  float mask = active ? 1.f : 0.f;
  float rs1 = 0.f, rs2 = 0.f;
#pragma unroll
  for (int d = 0; d < 64; ++d) {
    float a = y2[d] * mask;
    float bq = a * a;
#pragma unroll
    for (int m = 1; m < 64; m <<= 1) {
      a += __shfl_xor(a, m, 64);
      bq += __shfl_xor(bq, m, 64);
    }
    if (lane == d) { rs1 = a; rs2 = bq; }
  }
  sred[0][w][lane] = rs1;
  sred[1][w][lane] = rs2;
  __syncthreads();
  if (tid < 64) {
    atomicAdd(&stat[tid],
              sred[0][0][tid] + sred[0][1][tid] + sred[0][2][tid] + sred[0][3][tid]);
  } else if (tid < 128) {
    int cc = tid - 64;
    atomicAdd(&stat[64 + cc],
              sred[1][0][cc] + sred[1][1][cc] + sred[1][2][cc] + sred[1][3][cc]);
  }
}

// ---------------- BN finalize ----------------------------------------------
__global__ __launch_bounds__(64) void bnfinal_kernel(
    const float* __restrict__ stat, const float* __restrict__ gamma,
    const float* __restrict__ beta, float* __restrict__ scsh, float invN)
{
  int d = threadIdx.x;
  float mu = stat[d] * invN;
  float var = stat[64 + d] * invN - mu * mu;
  var = fmaxf(var, 0.f);
  float sc = gamma[d] * rsqrtf(var + 1e-5f);
  scsh[d] = sc;
  scsh[64 + d] = beta[d] - mu * sc;
}

// ---------------- pooling (fused BN-normalize + relu) ----------------------
__global__ __launch_bounds__(256) void pool_kernel(
    const u16* __restrict__ zb, const float* __restrict__ scsh,
    const int* __restrict__ batch,
    float* __restrict__ sums, float* __restrict__ cnts, int N)
{
  int lane = threadIdx.x & 63;
  int wave = (blockIdx.x * blockDim.x + threadIdx.x) >> 6;
  int r0 = wave * 64;
  if (r0 >= N) return;
  float sc = scsh[lane], sh = scsh[64 + lane];
  int r1 = min(r0 + 64, N);
  int cur = batch[r0];
  float acc = 0.f;
  int cnt = 0;
  for (int r = r0; r < r1; ++r) {
    int bg = batch[r];
    if (bg != cur) {
      atomicAdd(&sums[(size_t)cur * 64 + lane], acc);
      if (lane == 0) atomicAdd(&cnts[cur], (float)cnt);
      acc = 0.f; cnt = 0; cur = bg;
    }
    acc += fmaxf(fmaf(bf2f(zb[(size_t)r * 64 + lane]), sc, sh), 0.f);
    cnt++;
  }
  atomicAdd(&sums[(size_t)cur * 64 + lane], acc);
  if (lane == 0) atomicAdd(&cnts[cur], (float)cnt);
}

// ---------------- head: per-graph MLP --------------------------------------
__global__ __launch_bounds__(256) void head_kernel(
    const float* __restrict__ sums, const float* __restrict__ cnts,
    const float* __restrict__ W1, const float* __restrict__ b1,
    const float* __restrict__ W2, const float* __restrict__ b2,
    const float* __restrict__ W3, const float* __restrict__ b3,
    float* __restrict__ out)
{
  __shared__ float gf[128];
  __shared__ float h1s[256];
  __shared__ float h2s[128];
  int g = blockIdx.x, t = threadIdx.x;
  if (t < 64) {
    float sv = sums[(size_t)g * 64 + t];
    gf[t] = sv;
    gf[64 + t] = sv / fmaxf(cnts[g], 1.f);
  }
  __syncthreads();
  float a = b1[t];
  for (int k = 0; k < 128; ++k) a = fmaf(gf[k], W1[k * 256 + t], a);
  h1s[t] = fmaxf(a, 0.f);
  __syncthreads();
  if (t < 128) {
    float a2 = b2[t];
    for (int k = 0; k < 256; ++k) a2 = fmaf(h1s[k], W2[k * 128 + t], a2);
    h2s[t] = fmaxf(a2, 0.f);
  }
  __syncthreads();
  if (t == 0) {
    float s = b3[0];
    for (int k = 0; k < 128; ++k) s = fmaf(h2s[k], W3[k], s);
    out[g] = s;
  }
}

// ---------------------------------------------------------------------------
extern "C" void kernel_launch(void* const* d_in, const int* in_sizes, int n_in,
                              void* d_out, int out_size, void* d_ws, size_t ws_size,
                              hipStream_t stream)
{
  const float* x         = (const float*)d_in[0];
  const float* edge_attr = (const float*)d_in[1];
  const int*   ei        = (const int*)  d_in[2];
  const int*   batch     = (const int*)  d_in[3];
  const float* node_W    = (const float*)d_in[4];
  const float* node_b    = (const float*)d_in[5];
  const float* edge_W    = (const float*)d_in[6];
  const float* edge_b    = (const float*)d_in[7];
  const float* mlp1_W    = (const float*)d_in[8];
  const float* mlp1_b    = (const float*)d_in[9];
  const float* mlp2_W    = (const float*)d_in[10];
  const float* mlp2_b    = (const float*)d_in[11];
  const float* bn_gamma  = (const float*)d_in[12];
  const float* bn_beta   = (const float*)d_in[13];
  const float* head1_W   = (const float*)d_in[14];
  const float* head1_b   = (const float*)d_in[15];
  const float* head2_W   = (const float*)d_in[16];
  const float* head2_b   = (const float*)d_in[17];
  const float* head3_W   = (const float*)d_in[18];
  const float* head3_b   = (const float*)d_in[19];
  float* out = (float*)d_out;
  (void)n_in; (void)out_size;

  const int N = in_sizes[0] / 32;       // 100000
  const int E = in_sizes[2] / 2;        // 1600000
  const int* srcp = ei;
  const int* dstp = ei + E;

  auto al = [](size_t b) { return (b + 255) & ~(size_t)255; };
  const size_t sz_zb   = al((size_t)N * 64 * 2);   // bf16 activations
  const size_t sz_g    = al((size_t)N * 64 * 4);   // f32 gather output
  const size_t sz_as   = al((size_t)E * 16 * 2);   // bf16 sorted attrs
  const size_t sz_src  = al((size_t)E * 4);
  const size_t sz_rowp = al((size_t)(N + 1) * 4);
  const size_t sz_eids = al((size_t)E * 4);
  const size_t sz_small = al(512) * 3 + al(NGRAPH * 64 * 4) + al(NGRAPH * 4);

  const size_t need_sorted = sz_zb + sz_g + sz_as + sz_src + sz_rowp + sz_small;
  const bool sorted = ws_size >= need_sorted;

  char* p = (char*)d_ws;
  auto take = [&](size_t b) -> char* { char* q = p; p += b; return q; };

  u16*   zb   = (u16*)  take(sz_zb);
  float* gbuf = (float*)take(sz_g);
  int*   rowp = (int*)  take(sz_rowp);
  float* stat = (float*)take(al(512));
  float* scsh = (float*)take(al(512));
  int*   bsum = (int*)  take(al(512));
  float* sums = (float*)take(al(NGRAPH * 64 * 4));
  float* cnts = (float*)take(al(NGRAPH * 4));

  u32x4* attr_s4 = nullptr;
  int*   src_s   = nullptr;
  int*   eids    = nullptr;
  int* deg;
  int* fill;
  if (sorted) {
    attr_s4 = (u32x4*)take(sz_as);
    src_s   = (int*)take(sz_src);
    // scratch (dead after scatter) aliases gbuf (25.6 MB >= 0.8 MB)
    deg  = (int*)gbuf;
    fill = (int*)((char*)gbuf + al((size_t)N * 4));
  } else {
    src_s = (int*)take(sz_src);
    eids  = (int*)take(sz_eids);
    deg  = (int*)gbuf;
    fill = (int*)((char*)gbuf + al((size_t)N * 4));
  }

  const int NB = (N + SCAN_B - 1) / SCAN_B;

  // ---- encoders + CSR build ----
  hipMemsetAsync(deg,  0, (size_t)N * 4, stream);
  hipMemsetAsync(fill, 0, (size_t)N * 4, stream);

  node_enc_kernel<<<2048, 256, 0, stream>>>(x, node_W, node_b, zb, N);
  count_kernel<<<(E + 255) / 256, 256, 0, stream>>>(dstp, deg, E);
  scan1_kernel<<<NB, SCAN_B, 0, stream>>>(deg, rowp, bsum, N);
  scan2_kernel<<<1, 128, 0, stream>>>(bsum, NB);
  scan3_kernel<<<NB, SCAN_B, 0, stream>>>(rowp, bsum, N, E);
  scatter_conv_kernel<<<(E + 255) / 256, 256, 0, stream>>>(
      dstp, srcp, (const float4*)edge_attr, rowp, fill, src_s, attr_s4, eids, E);

  // ---- 4 GINE layers ----
  const int gatherBlocks = (N + 3) / 4;
  const int mlpBlocks    = (N + 255) / 256;
  for (int l = 0; l < 4; ++l) {
    if (sorted) {
      gather_kernel<<<gatherBlocks, 256, 0, stream>>>(
          (const u32*)zb, scsh, attr_s4, src_s, rowp, edge_W, edge_b,
          gbuf, N, l > 0);
    } else {
      gather_fallback_kernel<<<gatherBlocks, 256, 0, stream>>>(
          zb, scsh, src_s, eids, rowp, edge_attr, edge_W, edge_b, gbuf, N, l > 0);
    }
    hipMemsetAsync(stat, 0, 512, stream);
    mlp_fused_kernel<<<mlpBlocks, 256, 0, stream>>>(
        gbuf, zb, mlp1_W + (size_t)l * 4096, mlp1_b + (size_t)l * 64,
        mlp2_W + (size_t)l * 4096, mlp2_b + (size_t)l * 64, stat, N);
    bnfinal_kernel<<<1, 64, 0, stream>>>(
        stat, bn_gamma + (size_t)l * 64, bn_beta + (size_t)l * 64, scsh,
        1.0f / (float)N);
  }

  // ---- pooling + head ----
  hipMemsetAsync(sums, 0, (size_t)NGRAPH * 64 * 4, stream);
  hipMemsetAsync(cnts, 0, (size_t)NGRAPH * 4, stream);
  const int poolWaves = (N + 63) / 64;
  pool_kernel<<<(poolWaves + 3) / 4, 256, 0, stream>>>(zb, scsh, batch, sums, cnts, N);
  head_kernel<<<NGRAPH, 256, 0, stream>>>(
      sums, cnts, head1_W, head1_b, head2_W, head2_b, head3_W, head3_b, out);
}

// Round 6
// 1088.877 us; speedup vs baseline: 1.1958x; 1.1958x over previous
//
#include <hip/hip_runtime.h>

#define SCAN_B 1024
#define NGRAPH 128
typedef unsigned short u16;
typedef unsigned int u32;
typedef u32 u32x4 __attribute__((ext_vector_type(4)));
typedef _Float16 f16;
typedef _Float16 f16x2 __attribute__((ext_vector_type(2)));

__device__ __forceinline__ u16 f2h(float f) {
  f16 h = (f16)f;
  return __builtin_bit_cast(u16, h);
}
__device__ __forceinline__ float h2f(u16 u) {
  return (float)__builtin_bit_cast(f16, u);
}
__device__ __forceinline__ float hlo(u32 w) { return h2f((u16)(w & 0xffffu)); }
__device__ __forceinline__ float hhi(u32 w) { return h2f((u16)(w >> 16)); }

__device__ __forceinline__ float fdot2h(u32 a, u32 b, float c) {
#if __has_builtin(__builtin_amdgcn_fdot2)
  return __builtin_amdgcn_fdot2(__builtin_bit_cast(f16x2, a),
                                __builtin_bit_cast(f16x2, b), c, false);
#else
  f16x2 av = __builtin_bit_cast(f16x2, a), bv = __builtin_bit_cast(f16x2, b);
  return c + (float)av[0] * (float)bv[0] + (float)av[1] * (float)bv[1];
#endif
}

// ---------------- node encoder: h = x @ W(32x64) + b  -> f16 ---------------
__global__ __launch_bounds__(256) void node_enc_kernel(
    const float* __restrict__ x, const float* __restrict__ W,
    const float* __restrict__ b, u16* __restrict__ zh, int N)
{
  int lane = threadIdx.x & 63;
  int wave = (blockIdx.x * blockDim.x + threadIdx.x) >> 6;
  int nw = (gridDim.x * blockDim.x) >> 6;
  float wcol[32];
#pragma unroll
  for (int k = 0; k < 32; ++k) wcol[k] = W[k * 64 + lane];
  float bb = b[lane];
  for (int n = wave; n < N; n += nw) {
    const float4* xr = (const float4*)(x + (size_t)n * 32);
    float acc = bb;
#pragma unroll
    for (int c = 0; c < 8; ++c) {
      float4 v = xr[c];
      acc = fmaf(v.x, wcol[4 * c + 0], acc);
      acc = fmaf(v.y, wcol[4 * c + 1], acc);
      acc = fmaf(v.z, wcol[4 * c + 2], acc);
      acc = fmaf(v.w, wcol[4 * c + 3], acc);
    }
    zh[(size_t)n * 64 + lane] = f2h(acc);
  }
}

// ---------------- CSR build ------------------------------------------------
__global__ __launch_bounds__(256) void count_kernel(
    const int* __restrict__ dst, int* __restrict__ deg, int E)
{
  int e = blockIdx.x * blockDim.x + threadIdx.x;
  if (e < E) atomicAdd(&deg[dst[e]], 1);
}

__global__ __launch_bounds__(SCAN_B) void scan1_kernel(
    const int* __restrict__ deg, int* __restrict__ rowp,
    int* __restrict__ bsum, int N)
{
  __shared__ int s[SCAN_B];
  int tid = threadIdx.x;
  int i = blockIdx.x * SCAN_B + tid;
  int v = (i < N) ? deg[i] : 0;
  s[tid] = v;
  __syncthreads();
  for (int off = 1; off < SCAN_B; off <<= 1) {
    int t = (tid >= off) ? s[tid - off] : 0;
    __syncthreads();
    s[tid] += t;
    __syncthreads();
  }
  if (i < N) rowp[i] = s[tid] - v;          // exclusive
  if (tid == SCAN_B - 1) bsum[blockIdx.x] = s[tid];
}

__global__ __launch_bounds__(128) void scan2_kernel(int* __restrict__ bsum, int NB)
{
  __shared__ int s[128];
  int tid = threadIdx.x;
  int v = (tid < NB) ? bsum[tid] : 0;
  s[tid] = v;
  __syncthreads();
  for (int off = 1; off < 128; off <<= 1) {
    int t = (tid >= off) ? s[tid - off] : 0;
    __syncthreads();
    s[tid] += t;
    __syncthreads();
  }
  if (tid < NB) bsum[tid] = s[tid] - v;     // exclusive block offsets
}

__global__ __launch_bounds__(SCAN_B) void scan3_kernel(
    int* __restrict__ rowp, const int* __restrict__ bsum, int N, int E)
{
  int i = blockIdx.x * SCAN_B + threadIdx.x;
  if (i < N) rowp[i] += bsum[blockIdx.x];
  if (i == 0) rowp[N] = E;
}

// scatter + attr f16 convert into CSR order
__global__ __launch_bounds__(256) void scatter_conv_kernel(
    const int* __restrict__ dst, const int* __restrict__ src,
    const float4* __restrict__ attr4, const int* __restrict__ rowp,
    int* __restrict__ fill, int* __restrict__ src_s,
    u32x4* __restrict__ attr_s4, int* __restrict__ eids, int E)
{
  int e = blockIdx.x * blockDim.x + threadIdx.x;
  if (e >= E) return;
  int d = dst[e];
  int p = rowp[d] + atomicAdd(&fill[d], 1);
  src_s[p] = src[e];
  if (eids) eids[p] = e;
  if (attr_s4) {
    float4 a0 = attr4[(size_t)e * 4 + 0];
    float4 a1 = attr4[(size_t)e * 4 + 1];
    float4 a2 = attr4[(size_t)e * 4 + 2];
    float4 a3 = attr4[(size_t)e * 4 + 3];
    u32x4 lo, hi;
    lo[0] = (u32)f2h(a0.x) | ((u32)f2h(a0.y) << 16);
    lo[1] = (u32)f2h(a0.z) | ((u32)f2h(a0.w) << 16);
    lo[2] = (u32)f2h(a1.x) | ((u32)f2h(a1.y) << 16);
    lo[3] = (u32)f2h(a1.z) | ((u32)f2h(a1.w) << 16);
    hi[0] = (u32)f2h(a2.x) | ((u32)f2h(a2.y) << 16);
    hi[1] = (u32)f2h(a2.z) | ((u32)f2h(a2.w) << 16);
    hi[2] = (u32)f2h(a3.x) | ((u32)f2h(a3.y) << 16);
    hi[3] = (u32)f2h(a3.z) | ((u32)f2h(a3.w) << 16);
    attr_s4[(size_t)p * 2 + 0] = lo;
    attr_s4[(size_t)p * 2 + 1] = hi;
  }
}

// ---------------- gather (grid-stride, pair-packed, dot2-f16) --------------
// g[i] = hval(z[i]) + sum_{e: dst=i} relu(hval(z[src_e]) + attr_e @ eW + eb)
__global__ __launch_bounds__(256, 4) void gather_kernel(
    const u32* __restrict__ z32, const float* __restrict__ scsh,
    const u32x4* __restrict__ attr_s4, const int* __restrict__ srcv,
    const int* __restrict__ rowp, const float* __restrict__ eW,
    const float* __restrict__ eb_, float* __restrict__ g, int N, int use_bn)
{
  int lane = threadIdx.x & 63;
  int c = lane & 31, hi = lane >> 5;
  int wave = (blockIdx.x * blockDim.x + threadIdx.x) >> 6;
  int nw = (gridDim.x * blockDim.x) >> 6;

  // packed f16 weight pairs for channels 2c, 2c+1 (pair (2j,2j+1) of K dim)
  u32 wpk0[8], wpk1[8];
#pragma unroll
  for (int j = 0; j < 8; ++j) {
    float2 wa = *(const float2*)&eW[(2 * j) * 64 + 2 * c];
    float2 wb = *(const float2*)&eW[(2 * j + 1) * 64 + 2 * c];
    wpk0[j] = (u32)f2h(wa.x) | ((u32)f2h(wb.x) << 16);
    wpk1[j] = (u32)f2h(wa.y) | ((u32)f2h(wb.y) << 16);
  }
  float2 eb2 = *(const float2*)&eb_[2 * c];
  float2 sc2 = make_float2(1.f, 1.f), sh2 = make_float2(0.f, 0.f);
  if (use_bn) {
    sc2 = *(const float2*)&scsh[2 * c];
    sh2 = *(const float2*)&scsh[64 + 2 * c];
  }

  auto edot2 = [&](u32x4 lo, u32x4 hb, float& m0, float& m1) {
    m0 = eb2.x; m1 = eb2.y;
#pragma unroll
    for (int j = 0; j < 4; ++j) {
      m0 = fdot2h(lo[j], wpk0[j], m0);
      m1 = fdot2h(lo[j], wpk1[j], m1);
    }
#pragma unroll
    for (int j = 0; j < 4; ++j) {
      m0 = fdot2h(hb[j], wpk0[4 + j], m0);
      m1 = fdot2h(hb[j], wpk1[4 + j], m1);
    }
  };
  auto hval2 = [&](u32 zu, float& h0, float& h1) {
    float z0 = hlo(zu), z1 = hhi(zu);
    if (use_bn) {
      h0 = fmaxf(fmaf(z0, sc2.x, sh2.x), 0.f);
      h1 = fmaxf(fmaf(z1, sc2.y, sh2.y), 0.f);
    } else { h0 = z0; h1 = z1; }
  };

  for (int node = wave; node < N; node += nw) {
    const int j0 = rowp[node], j1 = rowp[node + 1];
    float accx, accy;
    {
      float h0, h1;
      hval2(z32[(size_t)node * 32 + c], h0, h1);
      accx = hi ? 0.f : h0;
      accy = hi ? 0.f : h1;
    }
    for (int base = j0; base < j1; base += 64) {
      int nb = j1 - base; if (nb > 64) nb = 64;
      int iv = (lane < nb) ? srcv[base + lane] : 0;
      int np = nb >> 1;
      int t = 0;
      for (; t + 8 <= np; t += 8) {
        int ss[8]; u32 zu[8];
#pragma unroll
        for (int q = 0; q < 8; ++q) ss[q] = __shfl(iv, 2 * (t + q) + hi, 64);
#pragma unroll
        for (int q = 0; q < 8; ++q) zu[q] = z32[(size_t)ss[q] * 32 + c];
#pragma unroll
        for (int q = 0; q < 8; ++q) {
          size_t jj = (size_t)(base + 2 * (t + q) + hi) * 2;
          u32x4 alo = attr_s4[jj];
          u32x4 ahi = attr_s4[jj + 1];
          float m0, m1;
          edot2(alo, ahi, m0, m1);
          float h0, h1;
          hval2(zu[q], h0, h1);
          accx += fmaxf(h0 + m0, 0.f);
          accy += fmaxf(h1 + m1, 0.f);
        }
      }
      for (; t < np; ++t) {
        int s = __shfl(iv, 2 * t + hi, 64);
        u32 zu = z32[(size_t)s * 32 + c];
        size_t jj = (size_t)(base + 2 * t + hi) * 2;
        u32x4 alo = attr_s4[jj];
        u32x4 ahi = attr_s4[jj + 1];
        float m0, m1;
        edot2(alo, ahi, m0, m1);
        float h0, h1;
        hval2(zu, h0, h1);
        accx += fmaxf(h0 + m0, 0.f);
        accy += fmaxf(h1 + m1, 0.f);
      }
      if (nb & 1) {
        int s = __shfl(iv, nb - 1, 64);
        u32 zu = z32[(size_t)s * 32 + c];
        size_t jj = (size_t)(base + nb - 1) * 2;
        u32x4 alo = attr_s4[jj];
        u32x4 ahi = attr_s4[jj + 1];
        float m0, m1;
        edot2(alo, ahi, m0, m1);
        float h0, h1;
        hval2(zu, h0, h1);
        float a0 = fmaxf(h0 + m0, 0.f);
        float a1 = fmaxf(h1 + m1, 0.f);
        accx += hi ? 0.f : a0;
        accy += hi ? 0.f : a1;
      }
    }
    float rx = accx + __shfl_xor(accx, 32, 64);
    float ry = accy + __shfl_xor(accy, 32, 64);
    if (!hi) {
      float2 r; r.x = rx; r.y = ry;
      *(float2*)(g + (size_t)node * 64 + 2 * c) = r;
    }
  }
}

// ---------------- fallback gather (non-sorted, f32 attr recompute) ---------
__global__ __launch_bounds__(256) void gather_fallback_kernel(
    const u16* __restrict__ zh, const float* __restrict__ scsh,
    const int* __restrict__ srcv, const int* __restrict__ eids,
    const int* __restrict__ rowp, const float* __restrict__ attr,
    const float* __restrict__ eW, const float* __restrict__ eb_,
    float* __restrict__ g, int N, int use_bn)
{
  int lane = threadIdx.x & 63;
  int node = (blockIdx.x * blockDim.x + threadIdx.x) >> 6;
  if (node >= N) return;
  float sc = 1.f, sh = 0.f;
  if (use_bn) { sc = scsh[lane]; sh = scsh[64 + lane]; }
  auto hval = [&](float zz) -> float {
    float v = fmaf(zz, sc, sh);
    return use_bn ? fmaxf(v, 0.f) : v;
  };
  float wcol[16];
#pragma unroll
  for (int k = 0; k < 16; ++k) wcol[k] = eW[k * 64 + lane];
  float eb = eb_[lane];
  const int j0 = rowp[node], j1 = rowp[node + 1];
  float acc = hval(h2f(zh[(size_t)node * 64 + lane]));
  for (int j = j0; j < j1; ++j) {
    int eid = eids[j];
    int s = srcv[j];
    const float4* ar = (const float4*)(attr + (size_t)eid * 16);
    float4 a0 = ar[0], a1 = ar[1], a2 = ar[2], a3 = ar[3];
    float m = eb;
    m = fmaf(a0.x, wcol[0], m);  m = fmaf(a0.y, wcol[1], m);
    m = fmaf(a0.z, wcol[2], m);  m = fmaf(a0.w, wcol[3], m);
    m = fmaf(a1.x, wcol[4], m);  m = fmaf(a1.y, wcol[5], m);
    m = fmaf(a1.z, wcol[6], m);  m = fmaf(a1.w, wcol[7], m);
    m = fmaf(a2.x, wcol[8], m);  m = fmaf(a2.y, wcol[9], m);
    m = fmaf(a2.z, wcol[10], m); m = fmaf(a2.w, wcol[11], m);
    m = fmaf(a3.x, wcol[12], m); m = fmaf(a3.y, wcol[13], m);
    m = fmaf(a3.z, wcol[14], m); m = fmaf(a3.w, wcol[15], m);
    acc += fmaxf(hval(h2f(zh[(size_t)s * 64 + lane])) + m, 0.f);
  }
  g[(size_t)node * 64 + lane] = acc;
}

// ---------------- fused MLP (two 64x64 matmuls) + BN stats -----------------
__global__ __launch_bounds__(256, 2) void mlp_fused_kernel(
    const float* __restrict__ g, u16* __restrict__ zh,
    const float* __restrict__ W1, const float* __restrict__ b1,
    const float* __restrict__ W2, const float* __restrict__ b2,
    float* __restrict__ stat, int N)
{
  __shared__ float sred[2][4][64];
  int tid = threadIdx.x, lane = tid & 63, w = tid >> 6;
  int row = blockIdx.x * 256 + tid;
  bool active = row < N;
  int r = active ? row : (N - 1);

  float y1[64];
#pragma unroll
  for (int d = 0; d < 64; ++d) y1[d] = b1[d];
  const float4* gr = (const float4*)(g + (size_t)r * 64);
  for (int kk = 0; kk < 16; ++kk) {
    float4 v = gr[kk];
    const float* wp = W1 + kk * 256;
#pragma unroll
    for (int d = 0; d < 64; ++d)
      y1[d] += fmaf(v.x, wp[d], fmaf(v.y, wp[64 + d],
               fmaf(v.z, wp[128 + d], v.w * wp[192 + d])));
  }
#pragma unroll
  for (int d = 0; d < 64; ++d) y1[d] = fmaxf(y1[d], 0.f);

  float y2[64];
#pragma unroll
  for (int d = 0; d < 64; ++d) y2[d] = b2[d];
  for (int kk = 0; kk < 16; ++kk) {
    const float* wp = W2 + kk * 256;
    float vx = y1[4 * kk], vy = y1[4 * kk + 1];
    float vz = y1[4 * kk + 2], vw = y1[4 * kk + 3];
#pragma unroll
    for (int d = 0; d < 64; ++d)
      y2[d] += fmaf(vx, wp[d], fmaf(vy, wp[64 + d],
               fmaf(vz, wp[128 + d], vw * wp[192 + d])));
  }

  if (active) {
    u32 packed[32];
#pragma unroll
    for (int c = 0; c < 32; ++c)
      packed[c] = (u32)f2h(y2[2 * c]) | ((u32)f2h(y2[2 * c + 1]) << 16);
    uint4* zr = (uint4*)(zh + (size_t)row * 64);
#pragma unroll
    for (int c = 0; c < 8; ++c)
      zr[c] = make_uint4(packed[4 * c], packed[4 * c + 1],
                         packed[4 * c + 2], packed[4 * c + 3]);
  }

  float mask = active ? 1.f : 0.f;
  float rs1 = 0.f, rs2 = 0.f;
#pragma unroll
  for (int d = 0; d < 64; ++d) {
    float a = y2[d] * mask;
    float bq = a * a;
#pragma unroll
    for (int m = 1; m < 64; m <<= 1) {
      a += __shfl_xor(a, m, 64);
      bq += __shfl_xor(bq, m, 64);
    }
    if (lane == d) { rs1 = a; rs2 = bq; }
  }
  sred[0][w][lane] = rs1;
  sred[1][w][lane] = rs2;
  __syncthreads();
  if (tid < 64) {
    atomicAdd(&stat[tid],
              sred[0][0][tid] + sred[0][1][tid] + sred[0][2][tid] + sred[0][3][tid]);
  } else if (tid < 128) {
    int cc = tid - 64;
    atomicAdd(&stat[64 + cc],
              sred[1][0][cc] + sred[1][1][cc] + sred[1][2][cc] + sred[1][3][cc]);
  }
}

// ---------------- BN finalize ----------------------------------------------
__global__ __launch_bounds__(64) void bnfinal_kernel(
    const float* __restrict__ stat, const float* __restrict__ gamma,
    const float* __restrict__ beta, float* __restrict__ scsh, float invN)
{
  int d = threadIdx.x;
  float mu = stat[d] * invN;
  float var = stat[64 + d] * invN - mu * mu;
  var = fmaxf(var, 0.f);
  float sc = gamma[d] * rsqrtf(var + 1e-5f);
  scsh[d] = sc;
  scsh[64 + d] = beta[d] - mu * sc;
}

// ---------------- pooling (fused BN-normalize + relu) ----------------------
__global__ __launch_bounds__(256) void pool_kernel(
    const u16* __restrict__ zh, const float* __restrict__ scsh,
    const int* __restrict__ batch,
    float* __restrict__ sums, float* __restrict__ cnts, int N)
{
  int lane = threadIdx.x & 63;
  int wave = (blockIdx.x * blockDim.x + threadIdx.x) >> 6;
  int r0 = wave * 64;
  if (r0 >= N) return;
  float sc = scsh[lane], sh = scsh[64 + lane];
  int r1 = min(r0 + 64, N);
  int cur = batch[r0];
  float acc = 0.f;
  int cnt = 0;
  for (int r = r0; r < r1; ++r) {
    int bg = batch[r];
    if (bg != cur) {
      atomicAdd(&sums[(size_t)cur * 64 + lane], acc);
      if (lane == 0) atomicAdd(&cnts[cur], (float)cnt);
      acc = 0.f; cnt = 0; cur = bg;
    }
    acc += fmaxf(fmaf(h2f(zh[(size_t)r * 64 + lane]), sc, sh), 0.f);
    cnt++;
  }
  atomicAdd(&sums[(size_t)cur * 64 + lane], acc);
  if (lane == 0) atomicAdd(&cnts[cur], (float)cnt);
}

// ---------------- head: per-graph MLP --------------------------------------
__global__ __launch_bounds__(256) void head_kernel(
    const float* __restrict__ sums, const float* __restrict__ cnts,
    const float* __restrict__ W1, const float* __restrict__ b1,
    const float* __restrict__ W2, const float* __restrict__ b2,
    const float* __restrict__ W3, const float* __restrict__ b3,
    float* __restrict__ out)
{
  __shared__ float gf[128];
  __shared__ float h1s[256];
  __shared__ float h2s[128];
  int g = blockIdx.x, t = threadIdx.x;
  if (t < 64) {
    float sv = sums[(size_t)g * 64 + t];
    gf[t] = sv;
    gf[64 + t] = sv / fmaxf(cnts[g], 1.f);
  }
  __syncthreads();
  float a = b1[t];
  for (int k = 0; k < 128; ++k) a = fmaf(gf[k], W1[k * 256 + t], a);
  h1s[t] = fmaxf(a, 0.f);
  __syncthreads();
  if (t < 128) {
    float a2 = b2[t];
    for (int k = 0; k < 256; ++k) a2 = fmaf(h1s[k], W2[k * 128 + t], a2);
    h2s[t] = fmaxf(a2, 0.f);
  }
  __syncthreads();
  if (t == 0) {
    float s = b3[0];
    for (int k = 0; k < 128; ++k) s = fmaf(h2s[k], W3[k], s);
    out[g] = s;
  }
}

// ---------------------------------------------------------------------------
extern "C" void kernel_launch(void* const* d_in, const int* in_sizes, int n_in,
                              void* d_out, int out_size, void* d_ws, size_t ws_size,
                              hipStream_t stream)
{
  const float* x         = (const float*)d_in[0];
  const float* edge_attr = (const float*)d_in[1];
  const int*   ei        = (const int*)  d_in[2];
  const int*   batch     = (const int*)  d_in[3];
  const float* node_W    = (const float*)d_in[4];
  const float* node_b    = (const float*)d_in[5];
  const float* edge_W    = (const float*)d_in[6];
  const float* edge_b    = (const float*)d_in[7];
  const float* mlp1_W    = (const float*)d_in[8];
  const float* mlp1_b    = (const float*)d_in[9];
  const float* mlp2_W    = (const float*)d_in[10];
  const float* mlp2_b    = (const float*)d_in[11];
  const float* bn_gamma  = (const float*)d_in[12];
  const float* bn_beta   = (const float*)d_in[13];
  const float* head1_W   = (const float*)d_in[14];
  const float* head1_b   = (const float*)d_in[15];
  const float* head2_W   = (const float*)d_in[16];
  const float* head2_b   = (const float*)d_in[17];
  const float* head3_W   = (const float*)d_in[18];
  const float* head3_b   = (const float*)d_in[19];
  float* out = (float*)d_out;
  (void)n_in; (void)out_size;

  const int N = in_sizes[0] / 32;       // 100000
  const int E = in_sizes[2] / 2;        // 1600000
  const int* srcp = ei;
  const int* dstp = ei + E;

  auto al = [](size_t b) { return (b + 255) & ~(size_t)255; };
  const size_t sz_zh   = al((size_t)N * 64 * 2);   // f16 activations
  const size_t sz_g    = al((size_t)N * 64 * 4);   // f32 gather output
  const size_t sz_as   = al((size_t)E * 16 * 2);   // f16 sorted attrs
  const size_t sz_src  = al((size_t)E * 4);
  const size_t sz_rowp = al((size_t)(N + 1) * 4);
  const size_t sz_eids = al((size_t)E * 4);
  const size_t sz_small = al(512) * 3 + al(NGRAPH * 64 * 4) + al(NGRAPH * 4);

  const size_t need_sorted = sz_zh + sz_g + sz_as + sz_src + sz_rowp + sz_small;
  const bool sorted = ws_size >= need_sorted;

  char* p = (char*)d_ws;
  auto take = [&](size_t b) -> char* { char* q = p; p += b; return q; };

  u16*   zh   = (u16*)  take(sz_zh);
  float* gbuf = (float*)take(sz_g);
  int*   rowp = (int*)  take(sz_rowp);
  float* stat = (float*)take(al(512));
  float* scsh = (float*)take(al(512));
  int*   bsum = (int*)  take(al(512));
  float* sums = (float*)take(al(NGRAPH * 64 * 4));
  float* cnts = (float*)take(al(NGRAPH * 4));

  u32x4* attr_s4 = nullptr;
  int*   src_s   = nullptr;
  int*   eids    = nullptr;
  int* deg;
  int* fill;
  if (sorted) {
    attr_s4 = (u32x4*)take(sz_as);
    src_s   = (int*)take(sz_src);
    // scratch (dead after scatter) aliases gbuf (25.6 MB >= 0.8 MB)
    deg  = (int*)gbuf;
    fill = (int*)((char*)gbuf + al((size_t)N * 4));
  } else {
    src_s = (int*)take(sz_src);
    eids  = (int*)take(sz_eids);
    deg  = (int*)gbuf;
    fill = (int*)((char*)gbuf + al((size_t)N * 4));
  }

  const int NB = (N + SCAN_B - 1) / SCAN_B;

  // ---- encoders + CSR build ----
  hipMemsetAsync(deg,  0, (size_t)N * 4, stream);
  hipMemsetAsync(fill, 0, (size_t)N * 4, stream);

  node_enc_kernel<<<2048, 256, 0, stream>>>(x, node_W, node_b, zh, N);
  count_kernel<<<(E + 255) / 256, 256, 0, stream>>>(dstp, deg, E);
  scan1_kernel<<<NB, SCAN_B, 0, stream>>>(deg, rowp, bsum, N);
  scan2_kernel<<<1, 128, 0, stream>>>(bsum, NB);
  scan3_kernel<<<NB, SCAN_B, 0, stream>>>(rowp, bsum, N, E);
  scatter_conv_kernel<<<(E + 255) / 256, 256, 0, stream>>>(
      dstp, srcp, (const float4*)edge_attr, rowp, fill, src_s, attr_s4, eids, E);

  // ---- 4 GINE layers ----
  const int mlpBlocks = (N + 255) / 256;
  for (int l = 0; l < 4; ++l) {
    if (sorted) {
      gather_kernel<<<2048, 256, 0, stream>>>(
          (const u32*)zh, scsh, attr_s4, src_s, rowp, edge_W, edge_b,
          gbuf, N, l > 0);
    } else {
      gather_fallback_kernel<<<(N + 3) / 4, 256, 0, stream>>>(
          zh, scsh, src_s, eids, rowp, edge_attr, edge_W, edge_b, gbuf, N, l > 0);
    }
    hipMemsetAsync(stat, 0, 512, stream);
    mlp_fused_kernel<<<mlpBlocks, 256, 0, stream>>>(
        gbuf, zh, mlp1_W + (size_t)l * 4096, mlp1_b + (size_t)l * 64,
        mlp2_W + (size_t)l * 4096, mlp2_b + (size_t)l * 64, stat, N);
    bnfinal_kernel<<<1, 64, 0, stream>>>(
        stat, bn_gamma + (size_t)l * 64, bn_beta + (size_t)l * 64, scsh,
        1.0f / (float)N);
  }

  // ---- pooling + head ----
  hipMemsetAsync(sums, 0, (size_t)NGRAPH * 64 * 4, stream);
  hipMemsetAsync(cnts, 0, (size_t)NGRAPH * 4, stream);
  const int poolWaves = (N + 63) / 64;
  pool_kernel<<<(poolWaves + 3) / 4, 256, 0, stream>>>(zh, scsh, batch, sums, cnts, N);
  head_kernel<<<NGRAPH, 256, 0, stream>>>(
      sums, cnts, head1_W, head1_b, head2_W, head2_b, head3_W, head3_b, out);
}